// Round 4
// baseline (559.154 us; speedup 1.0000x reference)
//
#include <hip/hip_runtime.h>

// ConvGeodesic: B=50000, R=5, A=8, K=2, O=32, I=32
// conv[b,c,o] = sum_{r,a,i} p[b,r,a,i] * W[(r,a,i)][(c,o)]
//   W[(r,a,i)][(c,o)] = sum_k kernel[r, (c+a)%8, k, o, i]
//   p[b,r,a,i] = sum_t bary[b,r,a,t] * signal[b,r,a,t,i]
// out[b,:] = relu(conv)[b, argmax_c ||relu(conv)[b,c,:]||, :]

#define B_TOT 50000
#define TB 64          // b's per block
#define KTOT 1280      // r*a*i
#define NTOT 256       // c*o
#define PSTR 36        // p_lds row stride (16B aligned, conflict-free writes)
#define ASTR 260       // act row stride (16B aligned)

__device__ __align__(16) float W_buf[KTOT * NTOT];   // 1.31 MB, L2-resident

__global__ __launch_bounds__(256) void build_w_kernel(const float* __restrict__ kern) {
    int e = blockIdx.x * 256 + threadIdx.x;          // e = k*256 + n
    if (e >= KTOT * NTOT) return;
    int k = e >> 8;
    int n = e & 255;
    int r = k >> 8;          // k = (r*8+a)*32 + i
    int a = (k >> 5) & 7;
    int i = k & 31;
    int c = n >> 5;          // n = c*32 + o
    int o = n & 31;
    int a2 = (c + a) & 7;
    // kernel layout (R, A, K, O, I); kk stride = 32*32 = 1024
    const float* p = kern + ((((r * 8 + a2) * 2 + 0) * 32 + o) * 32 + i);
    W_buf[e] = p[0] + p[1024];
}

__global__ __launch_bounds__(256) void conv_geo_kernel(const float* __restrict__ sig,
                                                       const float* __restrict__ bary,
                                                       float* __restrict__ out) {
    // union: K-loop uses w_lds[32][256] + p_lds[64][36]; epilogue reuses as act[32][260]
    __shared__ __align__(16) float smem[32 * 256 + TB * PSTR];   // 41984 B
    float* w_lds = smem;
    float* p_lds = smem + 32 * 256;

    const int tid = threadIdx.x;
    const int tn = tid & 31;   // column-group lane
    const int tb = tid >> 5;   // b-group (0..7)
    const int b0 = blockIdx.x * TB;

    // thread owns b_local = tb + 8*jj (jj=0..7), n = tn*4 + e + 128*h (nn = h*4+e)
    float acc[8][8];
#pragma unroll
    for (int j = 0; j < 8; ++j)
#pragma unroll
        for (int n = 0; n < 8; ++n) acc[j][n] = 0.0f;

    for (int ra = 0; ra < 40; ++ra) {   // (r,a) = (ra>>3, ra&7); k-chunk = ra*32 + i
        __syncthreads();
        // ---- stage pullback rows: p[b][i] = sum_t bary*sig, lanes i-consecutive ----
#pragma unroll
        for (int it = 0; it < 8; ++it) {
            int bl = tb + 8 * it;
            int b = b0 + bl; if (b > B_TOT - 1) b = B_TOT - 1;   // clamp loads (stores guarded)
            size_t base = ((size_t)b * 40 + ra) * 96;            // signal[b,r,a,0,0]
            const float* bp = bary + ((size_t)b * 40 + ra) * 3;
            float v = bp[0] * sig[base + tn];
            v = fmaf(bp[1], sig[base + 32 + tn], v);
            v = fmaf(bp[2], sig[base + 64 + tn], v);
            p_lds[bl * PSTR + tn] = v;
        }
        // ---- stage W slab: 32KB linear copy, conflict-free ----
        {
            const float4* wsrc = (const float4*)(W_buf + ra * 32 * 256);
            float4* wdst = (float4*)w_lds;
#pragma unroll
            for (int q = 0; q < 8; ++q) wdst[q * 256 + tid] = wsrc[q * 256 + tid];
        }
        __syncthreads();
        // ---- register-blocked outer product over this chunk's 32 k's ----
#pragma unroll
        for (int kq = 0; kq < 8; ++kq) {
            float wreg[4][8];
#pragma unroll
            for (int d = 0; d < 4; ++d) {
                float4 w0 = *(const float4*)&w_lds[(kq * 4 + d) * 256 + tn * 4];
                float4 w1 = *(const float4*)&w_lds[(kq * 4 + d) * 256 + tn * 4 + 128];
                wreg[d][0] = w0.x; wreg[d][1] = w0.y; wreg[d][2] = w0.z; wreg[d][3] = w0.w;
                wreg[d][4] = w1.x; wreg[d][5] = w1.y; wreg[d][6] = w1.z; wreg[d][7] = w1.w;
            }
#pragma unroll
            for (int jj = 0; jj < 8; ++jj) {
                float4 pf = *(const float4*)&p_lds[(tb + 8 * jj) * PSTR + kq * 4]; // broadcast
                float pv[4] = {pf.x, pf.y, pf.z, pf.w};
#pragma unroll
                for (int d = 0; d < 4; ++d)
#pragma unroll
                    for (int nn = 0; nn < 8; ++nn)
                        acc[jj][nn] = fmaf(pv[d], wreg[d][nn], acc[jj][nn]);
            }
        }
    }

    // ---- relu ----
#pragma unroll
    for (int j = 0; j < 8; ++j)
#pragma unroll
        for (int n = 0; n < 8; ++n) acc[j][n] = fmaxf(acc[j][n], 0.0f);

    // ---- epilogue: norms + argmax + select, two 32-b passes through LDS ----
    float* act = smem;   // [32][ASTR]
#pragma unroll
    for (int ph = 0; ph < 2; ++ph) {
        __syncthreads();   // previous LDS consumers done
#pragma unroll
        for (int j2 = 0; j2 < 4; ++j2) {
            int jj = ph * 4 + j2;                 // b_local = tb + 8*jj in [ph*32, ph*32+32)
            int brow = tb + 8 * j2;               // row within pass
            *(float4*)&act[brow * ASTR + tn * 4] =
                make_float4(acc[jj][0], acc[jj][1], acc[jj][2], acc[jj][3]);
            *(float4*)&act[brow * ASTR + 128 + tn * 4] =
                make_float4(acc[jj][4], acc[jj][5], acc[jj][6], acc[jj][7]);
        }
        __syncthreads();
        // 8 lanes per b: lane c computes ||act[b,c,:]||^2
        int bb = tid >> 3;
        int c = tid & 7;
        float n2 = 0.0f;
#pragma unroll
        for (int q = 0; q < 8; ++q) {
            float4 v = *(const float4*)&act[bb * ASTR + c * 32 + q * 4];
            n2 = fmaf(v.x, v.x, n2); n2 = fmaf(v.y, v.y, n2);
            n2 = fmaf(v.z, v.z, n2); n2 = fmaf(v.w, v.w, n2);
        }
        int bc = c;
#pragma unroll
        for (int m = 1; m < 8; m <<= 1) {   // argmax, tie -> lowest c (numpy first-max)
            float on2 = __shfl_xor(n2, m, 64);
            int obc = __shfl_xor(bc, m, 64);
            if (on2 > n2 || (on2 == n2 && obc < bc)) { n2 = on2; bc = obc; }
        }
        int b = b0 + ph * 32 + bb;
        if (b < B_TOT) {
            float4 v = *(const float4*)&act[bb * ASTR + bc * 32 + (tid & 7) * 4];
            *(float4*)&out[(size_t)b * 32 + (tid & 7) * 4] = v;
        }
    }
}

extern "C" void kernel_launch(void* const* d_in, const int* in_sizes, int n_in,
                              void* d_out, int out_size, void* d_ws, size_t ws_size,
                              hipStream_t stream) {
    const float* sig  = (const float*)d_in[0];   // (B,R,A,3,I)
    const float* bary = (const float*)d_in[1];   // (B,R,A,3)
    const float* kern = (const float*)d_in[2];   // (R,A,K,O,I)
    float* out = (float*)d_out;                  // (B,O)

    build_w_kernel<<<(KTOT * NTOT) / 256, 256, 0, stream>>>(kern);
    conv_geo_kernel<<<(B_TOT + TB - 1) / TB, 256, 0, stream>>>(sig, bary, out);
}

// Round 5
// 235.502 us; speedup vs baseline: 2.3743x; 2.3743x over previous
//
#include <hip/hip_runtime.h>

// ConvGeodesic: B=50000, R=5, A=8, K=2, O=32, I=32
// conv[b,n] = sum_k p[b,k] * W[k,n]   (M=50000, K=1280, N=256)
//   p[b,(ra,i)] = sum_t bary[b,ra,t]*signal[b,ra,t,i]
//   W[(ra,i),(c,o)] = sum_kk kernel[r,(c+a)%8,kk,o,i]
// GEMM on bf16 MFMA via hi/lo split (4 terms, fp32 accumulate).
// out[b,:] = relu(conv)[b, argmax_c ||relu(conv)[b,c,:]||, :]

#define B_TOT 50000
#define NRA 40

typedef __attribute__((ext_vector_type(8))) short short8v;   // 8 bf16 (4 VGPRs)
typedef __attribute__((ext_vector_type(4))) float f32x4;

// W planes, n-major k-minor per ra-slab: [ra][n=256][k'=32] bf16 (1.31 MB total)
__device__ __align__(16) unsigned short W_hi_g[NRA * 256 * 32];
__device__ __align__(16) unsigned short W_lo_g[NRA * 256 * 32];

static __device__ __forceinline__ unsigned short f2bf(float x) {   // rne
    unsigned u = __float_as_uint(x);
    u += 0x7FFFu + ((u >> 16) & 1u);
    return (unsigned short)(u >> 16);
}
static __device__ __forceinline__ float bf2f(unsigned short h) {
    return __uint_as_float(((unsigned)h) << 16);
}

__global__ __launch_bounds__(256) void build_w_kernel(const float* __restrict__ kern) {
    int e = blockIdx.x * 256 + threadIdx.x;   // e = ((ra*256)+n)*32 + i
    int i = e & 31;
    int n = (e >> 5) & 255;
    int ra = e >> 13;
    int r = ra >> 3, a = ra & 7;
    int c = n >> 5, o = n & 31;
    int a2 = (c + a) & 7;
    // kernel (R,A,K,O,I); kk stride = 1024
    const float* p = kern + ((((r * 8 + a2) * 2) * 32 + o) * 32 + i);
    float w = p[0] + p[1024];
    unsigned short hi = f2bf(w);
    unsigned short lo = f2bf(w - bf2f(hi));
    W_hi_g[e] = hi;
    W_lo_g[e] = lo;
}

static __device__ __forceinline__ void pcomp(float by0, float by1, float by2,
                                             const float4& a, const float4& b,
                                             const float4& c, float* d) {
    d[0] = fmaf(by2, c.x, fmaf(by1, b.x, by0 * a.x));
    d[1] = fmaf(by2, c.y, fmaf(by1, b.y, by0 * a.y));
    d[2] = fmaf(by2, c.z, fmaf(by1, b.z, by0 * a.z));
    d[3] = fmaf(by2, c.w, fmaf(by1, b.w, by0 * a.w));
}

static __device__ __forceinline__ void pack_write(unsigned short* p_hi, int idx, const float* v) {
    unsigned short h[4], l[4];
#pragma unroll
    for (int k = 0; k < 4; ++k) {
        h[k] = f2bf(v[k]);
        l[k] = f2bf(v[k] - bf2f(h[k]));
    }
    uint2 H, L;
    H.x = (unsigned)h[0] | ((unsigned)h[1] << 16);
    H.y = (unsigned)h[2] | ((unsigned)h[3] << 16);
    L.x = (unsigned)l[0] | ((unsigned)l[1] << 16);
    L.y = (unsigned)l[2] | ((unsigned)l[3] << 16);
    *(uint2*)(p_hi + idx) = H;            // hi plane
    *(uint2*)(p_hi + 2560 + idx) = L;     // lo plane (64*40 ushorts later)
}

__global__ __launch_bounds__(256, 3) void conv_geo_kernel(const float* __restrict__ sig,
                                                          const float* __restrict__ bary,
                                                          float* __restrict__ out) {
    // LDS union: K-loop p tiles (2 planes x [64][40] bf16 = 10240 B);
    // epilogue act half-tile [32][264] f32 = 33792 B.
    __shared__ __align__(16) float smem[8448];
    unsigned short* p_hi = (unsigned short*)smem;   // row stride 40 ushorts (80 B)

    const int tid  = threadIdx.x;
    const int lane = tid & 63;
    const int wave = tid >> 6;       // 4 waves, wave w owns cols [64w, 64w+64)
    const int b_l  = tid >> 2;       // 0..63: staging row
    const int q    = tid & 3;
    const int b0   = blockIdx.x * 64;
    int bld = b0 + b_l; if (bld > B_TOT - 1) bld = B_TOT - 1;   // clamp loads; stores guarded
    const size_t sig_row = (size_t)bld * 40;

    f32x4 acc[4][4];                 // [mi][ni]
#pragma unroll
    for (int mi = 0; mi < 4; ++mi)
#pragma unroll
        for (int ni = 0; ni < 4; ++ni) acc[mi][ni] = (f32x4){0.f, 0.f, 0.f, 0.f};

    // prologue: prefetch signal+bary for ra=0
    float4 s0, s1, s2, s3, s4, s5;
    float by0, by1, by2;
    {
        const float* sp = sig + sig_row * 96 + q * 4;
        s0 = *(const float4*)(sp);      s1 = *(const float4*)(sp + 16);
        s2 = *(const float4*)(sp + 32); s3 = *(const float4*)(sp + 48);
        s4 = *(const float4*)(sp + 64); s5 = *(const float4*)(sp + 80);
        const float* bp = bary + sig_row * 3;
        by0 = bp[0]; by1 = bp[1]; by2 = bp[2];
    }

    const int wcol = (wave * 64 + (lane & 15)) * 32 + (lane >> 4) * 8;  // ushort idx in slab
    const int poff = (lane & 15) * 40 + (lane >> 4) * 8;                // A-frag base (16B-aligned)
    const int widx = b_l * 40 + q * 4;                                  // p write base

    for (int ra = 0; ra < NRA; ++ra) {
        // ---- phase A: pullback -> bf16 hi/lo -> LDS (prev iter's reads fenced by loop-end barrier)
        float pa[4], pb[4];
        pcomp(by0, by1, by2, s0, s2, s4, pa);   // i = 4q..4q+3
        pcomp(by0, by1, by2, s1, s3, s5, pb);   // i = 4q+16..4q+19
        pack_write(p_hi, widx, pa);
        pack_write(p_hi, widx + 16, pb);

        // ---- phase B: B-frags global->VGPR (L2-hit, 1KB contiguous per frag); prefetch next signal
        short8v bh[4], blv[4];
        {
            const unsigned short* whp = W_hi_g + ra * 8192 + wcol;
            const unsigned short* wlp = W_lo_g + ra * 8192 + wcol;
#pragma unroll
            for (int ni = 0; ni < 4; ++ni) {
                bh[ni]  = *(const short8v*)(whp + ni * 512);
                blv[ni] = *(const short8v*)(wlp + ni * 512);
            }
        }
        if (ra < NRA - 1) {
            const float* sp = sig + (sig_row + ra + 1) * 96 + q * 4;
            s0 = *(const float4*)(sp);      s1 = *(const float4*)(sp + 16);
            s2 = *(const float4*)(sp + 32); s3 = *(const float4*)(sp + 48);
            s4 = *(const float4*)(sp + 64); s5 = *(const float4*)(sp + 80);
            const float* bp = bary + (sig_row + ra + 1) * 3;
            by0 = bp[0]; by1 = bp[1]; by2 = bp[2];
        }
        __syncthreads();
        // ---- phase C: A-frags from LDS + 4-term MFMA
#pragma unroll
        for (int mi = 0; mi < 4; ++mi) {
            const unsigned short* pr = p_hi + mi * 640 + poff;   // 16 rows * 40
            short8v ah = *(const short8v*)pr;
            short8v al = *(const short8v*)(pr + 2560);
#pragma unroll
            for (int ni = 0; ni < 4; ++ni) {
                acc[mi][ni] = __builtin_amdgcn_mfma_f32_16x16x32_bf16(ah, bh[ni],  acc[mi][ni], 0, 0, 0);
                acc[mi][ni] = __builtin_amdgcn_mfma_f32_16x16x32_bf16(ah, blv[ni], acc[mi][ni], 0, 0, 0);
                acc[mi][ni] = __builtin_amdgcn_mfma_f32_16x16x32_bf16(al, bh[ni],  acc[mi][ni], 0, 0, 0);
                acc[mi][ni] = __builtin_amdgcn_mfma_f32_16x16x32_bf16(al, blv[ni], acc[mi][ni], 0, 0, 0);
            }
        }
        __syncthreads();
    }

    // ---- epilogue: relu + norms + argmax + select, two 32-row passes through LDS ----
    // D layout: row = 16*mi + 4*(lane>>4) + j, col = 64*wave + 16*ni + (lane&15)   [m89-verified]
    const int colb = wave * 64 + (lane & 15);
    const int rsub = (lane >> 4) * 4;
#pragma unroll
    for (int ph = 0; ph < 2; ++ph) {
        __syncthreads();
#pragma unroll
        for (int mh = 0; mh < 2; ++mh) {
            int mi = ph * 2 + mh;
#pragma unroll
            for (int ni = 0; ni < 4; ++ni)
#pragma unroll
                for (int j = 0; j < 4; ++j)
                    smem[(mh * 16 + rsub + j) * 264 + colb + ni * 16] =
                        fmaxf(acc[mi][ni][j], 0.0f);
        }
        __syncthreads();
        int bb = tid >> 3;          // 0..31
        int c  = tid & 7;
        float n2 = 0.0f;
#pragma unroll
        for (int t = 0; t < 8; ++t) {
            float4 v = *(const float4*)&smem[bb * 264 + c * 32 + t * 4];
            n2 = fmaf(v.x, v.x, n2); n2 = fmaf(v.y, v.y, n2);
            n2 = fmaf(v.z, v.z, n2); n2 = fmaf(v.w, v.w, n2);
        }
        int bc = c;
#pragma unroll
        for (int m = 1; m < 8; m <<= 1) {   // argmax, tie -> lowest c (numpy first-max)
            float on2 = __shfl_xor(n2, m, 64);
            int obc = __shfl_xor(bc, m, 64);
            if (on2 > n2 || (on2 == n2 && obc < bc)) { n2 = on2; bc = obc; }
        }
        int b = b0 + ph * 32 + bb;
        if (b < B_TOT) {
            float4 v = *(const float4*)&smem[bb * 264 + bc * 32 + (tid & 7) * 4];
            *(float4*)&out[(size_t)b * 32 + (tid & 7) * 4] = v;
        }
    }
}

extern "C" void kernel_launch(void* const* d_in, const int* in_sizes, int n_in,
                              void* d_out, int out_size, void* d_ws, size_t ws_size,
                              hipStream_t stream) {
    const float* sig  = (const float*)d_in[0];   // (B,R,A,3,I)
    const float* bary = (const float*)d_in[1];   // (B,R,A,3)
    const float* kern = (const float*)d_in[2];   // (R,A,K,O,I)
    float* out = (float*)d_out;                  // (B,O)

    build_w_kernel<<<(NRA * 256 * 32) / 256, 256, 0, stream>>>(kern);
    conv_geo_kernel<<<(B_TOT + 63) / 64, 256, 0, stream>>>(sig, bary, out);
}

// Round 6
// 229.378 us; speedup vs baseline: 2.4377x; 1.0267x over previous
//
#include <hip/hip_runtime.h>

// ConvGeodesic: B=50000, R=5, A=8, K=2, O=32, I=32
// conv[b,n] = sum_k p[b,k] * W[k,n]   (M=50000, K=1280, N=256)
//   p[b,(ra,i)] = sum_t bary[b,ra,t]*signal[b,ra,t,i]
//   W[(ra,i),(c,o)] = sum_kk kernel[r,(c+a)%8,kk,o,i]
// GEMM on bf16 MFMA via hi/lo split, 3 terms (hi*hi + hi*lo + lo*hi; lo*lo ~2^-18 rel, dropped).
// Single barrier per K-step, double-buffered p tile in LDS.
// out[b,:] = relu(conv)[b, argmax_c ||relu(conv)[b,c,:]||, :]

#define B_TOT 50000
#define NRA 40

typedef __attribute__((ext_vector_type(8))) short short8v;   // 8 bf16 (4 VGPRs)
typedef __attribute__((ext_vector_type(4))) float f32x4;

// W planes, n-major k-minor per ra-slab: [ra][n=256][k'=32] bf16 (1.31 MB each)
__device__ __align__(16) unsigned short W_hi_g[NRA * 256 * 32];
__device__ __align__(16) unsigned short W_lo_g[NRA * 256 * 32];

static __device__ __forceinline__ unsigned short f2bf(float x) {   // rne
    unsigned u = __float_as_uint(x);
    u += 0x7FFFu + ((u >> 16) & 1u);
    return (unsigned short)(u >> 16);
}
static __device__ __forceinline__ float bf2f(unsigned short h) {
    return __uint_as_float(((unsigned)h) << 16);
}

__global__ __launch_bounds__(256) void build_w_kernel(const float* __restrict__ kern) {
    int e = blockIdx.x * 256 + threadIdx.x;   // e = ((ra*256)+n)*32 + i
    int i = e & 31;
    int n = (e >> 5) & 255;
    int ra = e >> 13;
    int r = ra >> 3, a = ra & 7;
    int c = n >> 5, o = n & 31;
    int a2 = (c + a) & 7;
    // kernel (R,A,K,O,I); kk stride = 1024
    const float* p = kern + ((((r * 8 + a2) * 2) * 32 + o) * 32 + i);
    float w = p[0] + p[1024];
    unsigned short hi = f2bf(w);
    unsigned short lo = f2bf(w - bf2f(hi));
    W_hi_g[e] = hi;
    W_lo_g[e] = lo;
}

static __device__ __forceinline__ void pcomp(float by0, float by1, float by2,
                                             const float4& a, const float4& b,
                                             const float4& c, float* d) {
    d[0] = fmaf(by2, c.x, fmaf(by1, b.x, by0 * a.x));
    d[1] = fmaf(by2, c.y, fmaf(by1, b.y, by0 * a.y));
    d[2] = fmaf(by2, c.z, fmaf(by1, b.z, by0 * a.z));
    d[3] = fmaf(by2, c.w, fmaf(by1, b.w, by0 * a.w));
}

static __device__ __forceinline__ void pack_write(unsigned short* buf, int idx, const float* v) {
    unsigned short h[4], l[4];
#pragma unroll
    for (int k = 0; k < 4; ++k) {
        h[k] = f2bf(v[k]);
        l[k] = f2bf(v[k] - bf2f(h[k]));
    }
    uint2 H, L;
    H.x = (unsigned)h[0] | ((unsigned)h[1] << 16);
    H.y = (unsigned)h[2] | ((unsigned)h[3] << 16);
    L.x = (unsigned)l[0] | ((unsigned)l[1] << 16);
    L.y = (unsigned)l[2] | ((unsigned)l[3] << 16);
    *(uint2*)(buf + idx) = H;            // hi plane
    *(uint2*)(buf + 2560 + idx) = L;     // lo plane (+64*40 ushorts)
}

__global__ __launch_bounds__(256, 3) void conv_geo_kernel(const float* __restrict__ sig,
                                                          const float* __restrict__ bary,
                                                          float* __restrict__ out) {
    // LDS union: two p buffers (hi+lo [64][40] bf16 = 10240 B each, 20480 B total);
    // epilogue act half-tile [32][264] f32 = 33792 B.
    __shared__ __align__(16) float smem[8448];
    unsigned short* pb0 = (unsigned short*)smem;          // buffer 0
    unsigned short* pb1 = pb0 + 5120;                     // buffer 1

    const int tid  = threadIdx.x;
    const int lane = tid & 63;
    const int wave = tid >> 6;       // 4 waves, wave w owns cols [64w, 64w+64)
    const int b_l  = tid >> 2;       // 0..63: staging row
    const int q    = tid & 3;
    const int b0   = blockIdx.x * 64;
    int bld = b0 + b_l; if (bld > B_TOT - 1) bld = B_TOT - 1;   // clamp loads; stores guarded
    const size_t sig_row = (size_t)bld * 40;

    f32x4 acc[4][4];                 // [mi][ni]
#pragma unroll
    for (int mi = 0; mi < 4; ++mi)
#pragma unroll
        for (int ni = 0; ni < 4; ++ni) acc[mi][ni] = (f32x4){0.f, 0.f, 0.f, 0.f};

    const int wcol = (wave * 64 + (lane & 15)) * 32 + (lane >> 4) * 8;  // B-frag ushort idx in slab
    const int poff = (lane & 15) * 40 + (lane >> 4) * 8;                // A-frag base (16B-aligned)
    const int widx = b_l * 40 + q * 4;                                  // p write base

    float4 s0, s1, s2, s3, s4, s5;
    float by0, by1, by2;
    auto load_sig = [&](int ra) {
        const float* sp = sig + (sig_row + ra) * 96 + q * 4;
        s0 = *(const float4*)(sp);      s1 = *(const float4*)(sp + 16);
        s2 = *(const float4*)(sp + 32); s3 = *(const float4*)(sp + 48);
        s4 = *(const float4*)(sp + 64); s5 = *(const float4*)(sp + 80);
        const float* bp = bary + (sig_row + ra) * 3;
        by0 = bp[0]; by1 = bp[1]; by2 = bp[2];
    };
    auto store_p = [&](unsigned short* wrbuf) {
        float pa[4], pbv[4];
        pcomp(by0, by1, by2, s0, s2, s4, pa);    // i = 4q..4q+3
        pcomp(by0, by1, by2, s1, s3, s5, pbv);   // i = 4q+16..4q+19
        pack_write(wrbuf, widx, pa);
        pack_write(wrbuf, widx + 16, pbv);
    };

    // prologue: p(0) -> pb0; sig regs hold sig(1)
    load_sig(0);
    store_p(pb0);
    load_sig(1);
    __syncthreads();

    // body invariant: rdbuf holds p(ra); sig regs hold sig(ra+1)
    auto body = [&](int ra, unsigned short* rdbuf, unsigned short* wrbuf) {
        // W frags for ra (L2-hit, contiguous 1KB per frag)
        short8v bh[4], bl[4];
        const unsigned short* whp = W_hi_g + ra * 8192 + wcol;
        const unsigned short* wlp = W_lo_g + ra * 8192 + wcol;
#pragma unroll
        for (int ni = 0; ni < 4; ++ni) {
            bh[ni] = *(const short8v*)(whp + ni * 512);
            bl[ni] = *(const short8v*)(wlp + ni * 512);
        }
        // pullback for ra+1 -> wrbuf (read next iter)
        if (ra + 1 < NRA) store_p(wrbuf);
        // prefetch signal for ra+2
        if (ra + 2 < NRA) load_sig(ra + 2);
        // A-frags + 3-term MFMA from rdbuf
#pragma unroll
        for (int mi = 0; mi < 4; ++mi) {
            const unsigned short* pr = rdbuf + mi * 640 + poff;   // 16 rows * 40
            short8v ah = *(const short8v*)pr;
            short8v al = *(const short8v*)(pr + 2560);
#pragma unroll
            for (int ni = 0; ni < 4; ++ni) {
                acc[mi][ni] = __builtin_amdgcn_mfma_f32_16x16x32_bf16(ah, bh[ni], acc[mi][ni], 0, 0, 0);
                acc[mi][ni] = __builtin_amdgcn_mfma_f32_16x16x32_bf16(ah, bl[ni], acc[mi][ni], 0, 0, 0);
                acc[mi][ni] = __builtin_amdgcn_mfma_f32_16x16x32_bf16(al, bh[ni], acc[mi][ni], 0, 0, 0);
            }
        }
        __syncthreads();   // single barrier per K-step
    };

    for (int ra = 0; ra < NRA; ra += 2) {
        body(ra,     pb0, pb1);
        body(ra + 1, pb1, pb0);
    }

    // ---- epilogue: relu + norms + argmax + select, two 32-row passes through LDS ----
    // D layout: row = 16*mi + 4*(lane>>4) + j, col = 64*wave + 16*ni + (lane&15)   [m89-verified]
    const int colb = wave * 64 + (lane & 15);
    const int rsub = (lane >> 4) * 4;
#pragma unroll
    for (int ph = 0; ph < 2; ++ph) {
        __syncthreads();
#pragma unroll
        for (int mh = 0; mh < 2; ++mh) {
            int mi = ph * 2 + mh;
#pragma unroll
            for (int ni = 0; ni < 4; ++ni)
#pragma unroll
                for (int j = 0; j < 4; ++j)
                    smem[(mh * 16 + rsub + j) * 264 + colb + ni * 16] =
                        fmaxf(acc[mi][ni][j], 0.0f);
        }
        __syncthreads();
        int bb = tid >> 3;          // 0..31
        int c  = tid & 7;
        float n2 = 0.0f;
#pragma unroll
        for (int t = 0; t < 8; ++t) {
            float4 v = *(const float4*)&smem[bb * 264 + c * 32 + t * 4];
            n2 = fmaf(v.x, v.x, n2); n2 = fmaf(v.y, v.y, n2);
            n2 = fmaf(v.z, v.z, n2); n2 = fmaf(v.w, v.w, n2);
        }
        int bc = c;
#pragma unroll
        for (int m = 1; m < 8; m <<= 1) {   // argmax, tie -> lowest c (numpy first-max)
            float on2 = __shfl_xor(n2, m, 64);
            int obc = __shfl_xor(bc, m, 64);
            if (on2 > n2 || (on2 == n2 && obc < bc)) { n2 = on2; bc = obc; }
        }
        int b = b0 + ph * 32 + bb;
        if (b < B_TOT) {
            float4 v = *(const float4*)&smem[bb * 264 + bc * 32 + (tid & 7) * 4];
            *(float4*)&out[(size_t)b * 32 + (tid & 7) * 4] = v;
        }
    }
}

extern "C" void kernel_launch(void* const* d_in, const int* in_sizes, int n_in,
                              void* d_out, int out_size, void* d_ws, size_t ws_size,
                              hipStream_t stream) {
    const float* sig  = (const float*)d_in[0];   // (B,R,A,3,I)
    const float* bary = (const float*)d_in[1];   // (B,R,A,3)
    const float* kern = (const float*)d_in[2];   // (R,A,K,O,I)
    float* out = (float*)d_out;                  // (B,O)

    build_w_kernel<<<(NRA * 256 * 32) / 256, 256, 0, stream>>>(kern);
    conv_geo_kernel<<<(B_TOT + 63) / 64, 256, 0, stream>>>(sig, bary, out);
}